// Round 1
// baseline (468.159 us; speedup 1.0000x reference)
//
#include <hip/hip_runtime.h>
#include <stdint.h>

// Problem constants (FloodFillOperation_42580305773207): B=256, C=10, H=256, W=256 fp32
#define B_ 256
#define C_ 10
#define H_ 256
#define W_ 256
#define WPR 8            // 32-bit words per row (256 bits)
#define WPI 2048         // words per image bitmask (256 rows * 8)

// ---------------- Kernel 1: per-batch flood fill into a bitmask ----------------
// One block (256 threads) per batch image. Bitmask layout: word w covers pixels
// flat = h*256 + ww, word index = flat>>5 = h*8 + (ww>>5), bit = ww&31.
__global__ __launch_bounds__(256) void ff_mask_kernel(
    const float* __restrict__ grid,
    const int* __restrict__ p_sy,
    const int* __restrict__ p_sx,
    uint32_t* __restrict__ ws_mask,   // [B][WPI]
    int* __restrict__ ws_sc)          // [B]
{
  const int b    = blockIdx.x;
  const int tid  = threadIdx.x;
  const int lane = tid & 63;
  const int wv   = tid >> 6;

  __shared__ uint32_t cm[WPI];   // color mask bits
  __shared__ uint32_t m[WPI];    // flood mask bits
  __shared__ int s_sc, s_has, s_changed;

  const int sy = p_sy[0];
  const int sx = p_sx[0];

  if (tid == 0) {
    int sc = 0, has = 0;
    for (int c = 0; c < C_; ++c) {
      float v = grid[(((size_t)b * C_ + c) * H_ + sy) * W_ + sx];
      if (v > 0.5f) { sc = c; has = 1; break; }
    }
    s_sc = sc; s_has = has; s_changed = 0;
    ws_sc[b] = sc;
  }
  // zero flood mask
  for (int i = tid; i < WPI; i += 256) m[i] = 0u;
  __syncthreads();

  const int sc = s_sc;

  // Load seed-color channel as a bitmask via wave ballot:
  // chunk k covers 64 consecutive pixels -> words 2k, 2k+1.
  const float* ch = grid + ((size_t)b * C_ + sc) * (size_t)(H_ * W_);
  for (int k = wv; k < (H_ * W_ / 64); k += 4) {
    float v = ch[k * 64 + lane];
    unsigned long long bal = __ballot(v > 0.5f);
    if (lane == 0) {
      cm[2 * k]     = (uint32_t)bal;
      cm[2 * k + 1] = (uint32_t)(bal >> 32);
    }
  }
  __syncthreads();

  if (tid == 0 && s_has) {
    m[sy * WPR + (sx >> 5)] = 1u << (sx & 31);
  }
  __syncthreads();

  // Each thread owns one row. Iterate dilation to fixed point.
  const int r = tid;
  uint32_t cmr[WPR];
  #pragma unroll
  for (int j = 0; j < WPR; ++j) cmr[j] = cm[r * WPR + j];

  for (;;) {
    uint32_t cur[WPR], up[WPR], dn[WPR];
    #pragma unroll
    for (int j = 0; j < WPR; ++j) {
      cur[j] = m[r * WPR + j];
      up[j]  = (r > 0)        ? m[(r - 1) * WPR + j] : 0u;
      dn[j]  = (r < H_ - 1)   ? m[(r + 1) * WPR + j] : 0u;
    }
    bool ch = false;
    uint32_t nw[WPR];
    #pragma unroll
    for (int j = 0; j < WPR; ++j) {
      uint32_t lo = (cur[j] << 1) | (j > 0        ? (cur[j - 1] >> 31) : 0u);
      uint32_t hi = (cur[j] >> 1) | (j < WPR - 1  ? (cur[j + 1] << 31) : 0u);
      uint32_t v  = (cur[j] | lo | hi | up[j] | dn[j]) & cmr[j];
      nw[j] = v;
      ch |= (v != cur[j]);
    }
    if (ch) {
      #pragma unroll
      for (int j = 0; j < WPR; ++j) m[r * WPR + j] = nw[j];
      s_changed = 1;   // benign race: any 1 wins
    }
    __syncthreads();                 // B1: all writes visible
    bool done = (s_changed == 0);
    __syncthreads();                 // B2: everyone has read the flag
    if (done) break;
    if (tid == 0) s_changed = 0;
    __syncthreads();                 // B3: reset visible before next round's writes
  }

  // Dump mask to workspace (coalesced)
  for (int i = tid; i < WPI; i += 256) ws_mask[(size_t)b * WPI + i] = m[i];
}

// ---------------- Kernel 2: streamed apply/copy ----------------
__global__ __launch_bounds__(256) void ff_apply_kernel(
    const float4* __restrict__ gin,
    float4* __restrict__ gout,
    const uint32_t* __restrict__ ws_mask,
    const int* __restrict__ ws_sc,
    const int* __restrict__ p_tc,
    int n4)
{
  const int tc = p_tc[0];
  int i = blockIdx.x * 256 + threadIdx.x;
  const int stride = gridDim.x * 256;
  for (; i < n4; i += stride) {
    float4 v = gin[i];
    const int pix = i << 2;                  // flat pixel index (fits: <2^31)
    const int w   = pix & (W_ - 1);
    const int h   = (pix >> 8) & (H_ - 1);
    const int bc  = pix >> 16;               // b*C + c
    const int b   = bc / C_;
    const int c   = bc - b * C_;
    const int scb = ws_sc[b];
    if (c == scb || c == tc) {
      const uint32_t mw = ws_mask[b * WPI + h * WPR + (w >> 5)];
      const float rep = (c == tc) ? 1.0f : 0.0f;
      const int sh = w & 31;
      if ((mw >> (sh + 0)) & 1u) v.x = rep;
      if ((mw >> (sh + 1)) & 1u) v.y = rep;
      if ((mw >> (sh + 2)) & 1u) v.z = rep;
      if ((mw >> (sh + 3)) & 1u) v.w = rep;
    }
    gout[i] = v;
  }
}

extern "C" void kernel_launch(void* const* d_in, const int* in_sizes, int n_in,
                              void* d_out, int out_size, void* d_ws, size_t ws_size,
                              hipStream_t stream) {
  const float* grid = (const float*)d_in[0];
  const int* p_sy   = (const int*)d_in[1];
  const int* p_sx   = (const int*)d_in[2];
  const int* p_tc   = (const int*)d_in[3];
  float* out        = (float*)d_out;

  uint32_t* ws_mask = (uint32_t*)d_ws;                       // B*WPI words = 2 MB
  int* ws_sc        = (int*)((char*)d_ws + (size_t)B_ * WPI * sizeof(uint32_t));

  // Kernel 1: flood fill per batch
  ff_mask_kernel<<<B_, 256, 0, stream>>>(grid, p_sy, p_sx, ws_mask, ws_sc);

  // Kernel 2: streamed apply (float4)
  const int n4 = (B_ * C_ * H_ * W_) / 4;
  ff_apply_kernel<<<2048, 256, 0, stream>>>(
      (const float4*)grid, (float4*)out, ws_mask, ws_sc, p_tc, n4);
}

// Round 3
// 343.528 us; speedup vs baseline: 1.3628x; 1.3628x over previous
//
#include <hip/hip_runtime.h>
#include <stdint.h>

// FloodFillOperation: B=256, C=10, H=256, W=256 fp32
#define B_ 256
#define C_ 10
#define H_ 256
#define W_ 256
#define WPR 8            // 32-bit words per row (256 bits)
#define WPI 2048         // words per image bitmask (256 rows * 8)

typedef float f4 __attribute__((ext_vector_type(4)));   // true vector type (nontemporal-ok)

// spread 8 bits b[i] -> output bit 4i
__device__ __forceinline__ uint32_t spread4(uint32_t u) {
  u = (u | (u << 12)) & 0x000F000Fu;
  u = (u | (u << 6))  & 0x03030303u;
  u = (u | (u << 3))  & 0x11111111u;
  return u;
}

// ---------------- Kernel A: per-batch seed color ----------------
__global__ __launch_bounds__(256) void ff_seed_kernel(
    const float* __restrict__ grid,
    const int* __restrict__ p_sy, const int* __restrict__ p_sx,
    int* __restrict__ ws_sc, int* __restrict__ ws_has)
{
  const int b = blockIdx.x * 256 + threadIdx.x;
  if (b >= B_) return;
  const int sy = p_sy[0], sx = p_sx[0];
  int sc = 0, has = 0;
  // descending loop, unconditional independent loads; keeps LOWEST c with v>0.5
  #pragma unroll
  for (int c = C_ - 1; c >= 0; --c) {
    float v = grid[(((size_t)b * C_ + c) * H_ + sy) * W_ + sx];
    if (v > 0.5f) { sc = c; has = 1; }
  }
  ws_sc[b] = sc;
  ws_has[b] = has;
}

// ---------------- Kernel B: seed-channel -> bitmask (full occupancy) ----------------
// chunk = 256 consecutive floats of one image's seed channel = 8 mask words.
// One wave per chunk-iteration: coalesced float4 loads, 4 ballots, bit-spread.
__global__ __launch_bounds__(256) void ff_bitmask_kernel(
    const float* __restrict__ grid,
    const int* __restrict__ ws_sc,
    uint32_t* __restrict__ ws_cm)
{
  const int lane = threadIdx.x & 63;
  const int wv   = threadIdx.x >> 6;
  int gw = blockIdx.x * 4 + wv;
  const int nw = gridDim.x * 4;
  const int nchunks = B_ * H_ * W_ / 256;   // 65536
  for (int ck = gw; ck < nchunks; ck += nw) {
    const int b   = ck >> 8;        // 256 chunks per image
    const int cof = ck & 255;
    const int sc  = ws_sc[b];
    const float* ch = grid + ((size_t)b * C_ + sc) * (size_t)(H_ * W_) + cof * 256;
    f4 v = ((const f4*)ch)[lane];
    unsigned long long bx = __ballot(v.x > 0.5f);
    unsigned long long by = __ballot(v.y > 0.5f);
    unsigned long long bz = __ballot(v.z > 0.5f);
    unsigned long long bw = __ballot(v.w > 0.5f);
    if (lane < 8) {
      uint32_t word = spread4((uint32_t)(bx >> (8 * lane)) & 0xFFu)
                    | (spread4((uint32_t)(by >> (8 * lane)) & 0xFFu) << 1)
                    | (spread4((uint32_t)(bz >> (8 * lane)) & 0xFFu) << 2)
                    | (spread4((uint32_t)(bw >> (8 * lane)) & 0xFFu) << 3);
      ws_cm[(size_t)b * WPI + cof * 8 + lane] = word;
    }
  }
}

// ---------------- Kernel C: per-batch flood fill (LDS, column-major) ----------------
// LDS layout: word j of row r at [j*256 + r] -> neighbor reads are conflict-free.
__global__ __launch_bounds__(256) void ff_flood_kernel(
    const uint32_t* __restrict__ ws_cm,
    const int* __restrict__ ws_has,
    const int* __restrict__ p_sy, const int* __restrict__ p_sx,
    uint32_t* __restrict__ ws_mask)
{
  const int b = blockIdx.x, tid = threadIdx.x;
  __shared__ uint32_t cm[WPI];
  __shared__ uint32_t m[WPI];
  __shared__ int s_changed;

  const int sy = p_sy[0], sx = p_sx[0];

  // load color bitmask (global coalesced, LDS transposed to column-major)
  for (int i = tid; i < WPI; i += 256) {
    cm[(i & 7) * H_ + (i >> 3)] = ws_cm[(size_t)b * WPI + i];
    m[(i & 7) * H_ + (i >> 3)] = 0u;
  }
  if (tid == 0) {
    s_changed = 0;
    if (ws_has[b]) m[(sx >> 5) * H_ + sy] = 1u << (sx & 31);
  }
  __syncthreads();

  const int r = tid;   // row owned by this thread
  uint32_t cmr[WPR];
  #pragma unroll
  for (int j = 0; j < WPR; ++j) cmr[j] = cm[j * H_ + r];

  for (;;) {
    uint32_t cur[WPR], w_[WPR];
    #pragma unroll
    for (int j = 0; j < WPR; ++j) {
      uint32_t c0 = m[j * H_ + r];
      uint32_t up = (r > 0)      ? m[j * H_ + (r - 1)] : 0u;
      uint32_t dn = (r < H_ - 1) ? m[j * H_ + (r + 1)] : 0u;
      cur[j] = c0;
      w_[j] = (c0 | up | dn) & cmr[j];
    }
    // in-register horizontal saturation (same fixed point, fewer barrier rounds)
    for (bool hch = true; hch; ) {
      hch = false;
      #pragma unroll
      for (int j = 0; j < WPR; ++j) {
        uint32_t lo = (w_[j] << 1) | (j > 0       ? (w_[j - 1] >> 31) : 0u);
        uint32_t hi = (w_[j] >> 1) | (j < WPR - 1 ? (w_[j + 1] << 31) : 0u);
        uint32_t v = (w_[j] | lo | hi) & cmr[j];
        hch |= (v != w_[j]);
        w_[j] = v;
      }
    }
    bool ch = false;
    #pragma unroll
    for (int j = 0; j < WPR; ++j) ch |= (w_[j] != cur[j]);
    if (ch) {
      #pragma unroll
      for (int j = 0; j < WPR; ++j) m[j * H_ + r] = w_[j];
      s_changed = 1;                 // benign race: any 1 wins
    }
    __syncthreads();                 // B1: writes visible
    bool done = (s_changed == 0);
    __syncthreads();                 // B2: everyone read the flag
    if (done) break;
    if (tid == 0) s_changed = 0;
    __syncthreads();                 // B3: reset visible
  }

  // dump mask row-major (global coalesced)
  for (int i = tid; i < WPI; i += 256)
    ws_mask[(size_t)b * WPI + i] = m[(i & 7) * H_ + (i >> 3)];
}

// ---------------- Kernel D: streamed apply/copy ----------------
__global__ __launch_bounds__(256) void ff_apply_kernel(
    const f4* __restrict__ gin,
    f4* __restrict__ gout,
    const uint32_t* __restrict__ ws_mask,
    const int* __restrict__ ws_sc,
    const int* __restrict__ p_tc,
    int n4)
{
  const int tc = p_tc[0];
  int i = blockIdx.x * 256 + threadIdx.x;
  const int stride = gridDim.x * 256;
  for (; i < n4; i += stride) {
    f4 v = __builtin_nontemporal_load(&gin[i]);
    const int pix = i << 2;                  // flat float index
    const int w   = pix & (W_ - 1);
    const int h   = (pix >> 8) & (H_ - 1);
    const int bc  = pix >> 16;               // b*C + c
    const int b   = bc / C_;
    const int c   = bc - b * C_;
    const int scb = ws_sc[b];
    if (c == scb || c == tc) {
      const uint32_t mw = ws_mask[b * WPI + h * WPR + (w >> 5)];
      const float rep = (c == tc) ? 1.0f : 0.0f;   // target wins over seed-color
      const int sh = w & 31;
      if ((mw >> (sh + 0)) & 1u) v.x = rep;
      if ((mw >> (sh + 1)) & 1u) v.y = rep;
      if ((mw >> (sh + 2)) & 1u) v.z = rep;
      if ((mw >> (sh + 3)) & 1u) v.w = rep;
    }
    __builtin_nontemporal_store(v, &gout[i]);
  }
}

extern "C" void kernel_launch(void* const* d_in, const int* in_sizes, int n_in,
                              void* d_out, int out_size, void* d_ws, size_t ws_size,
                              hipStream_t stream) {
  const float* grid = (const float*)d_in[0];
  const int* p_sy   = (const int*)d_in[1];
  const int* p_sx   = (const int*)d_in[2];
  const int* p_tc   = (const int*)d_in[3];
  float* out        = (float*)d_out;

  // workspace layout
  uint32_t* ws_mask = (uint32_t*)d_ws;                                    // 2 MB
  uint32_t* ws_cm   = (uint32_t*)((char*)d_ws + 2u * 1024 * 1024);        // 2 MB
  int* ws_sc        = (int*)((char*)d_ws + 4u * 1024 * 1024);             // 1 KB
  int* ws_has       = (int*)((char*)d_ws + 4u * 1024 * 1024 + 4096);      // 1 KB

  ff_seed_kernel<<<1, 256, 0, stream>>>(grid, p_sy, p_sx, ws_sc, ws_has);
  ff_bitmask_kernel<<<2048, 256, 0, stream>>>(grid, ws_sc, ws_cm);
  ff_flood_kernel<<<B_, 256, 0, stream>>>(ws_cm, ws_has, p_sy, p_sx, ws_mask);

  const int n4 = (B_ * C_ * H_ * W_) / 4;
  ff_apply_kernel<<<2048, 256, 0, stream>>>(
      (const f4*)grid, (f4*)out, ws_mask, ws_sc, p_tc, n4);
}